// Round 3
// baseline (1990.240 us; speedup 1.0000x reference)
//
#include <hip/hip_runtime.h>

#define NN 4096
#define DD 128
#define REGC 0.05f
#define EPSC 1e-8f
#define NSINK 14
#define KPAD 144  // shorts; 288B row stride -> max 4-way LDS bank conflict on frag reads

typedef float f32x4 __attribute__((ext_vector_type(4)));
typedef float f32x2 __attribute__((ext_vector_type(2)));
typedef short s16x8 __attribute__((ext_vector_type(8)));

__device__ __forceinline__ float wave_reduce_sum(float s) {
#pragma unroll
  for (int m = 32; m >= 1; m >>= 1) s += __shfl_xor(s, m, 64);
  return s;
}

__device__ __forceinline__ short f32_to_bf16(float f) {
  union { float f; unsigned u; } x; x.f = f;
  unsigned r = (x.u + 0x7FFFu + ((x.u >> 16) & 1u)) >> 16;
  return (short)r;
}

__device__ __forceinline__ void fp8x4_decode(unsigned int k, float* o) {
  f32x2 lo = __builtin_amdgcn_cvt_pk_f32_fp8((int)k, false);
  f32x2 hi = __builtin_amdgcn_cvt_pk_f32_fp8((int)k, true);
  o[0] = lo[0]; o[1] = lo[1]; o[2] = hi[0]; o[3] = hi[1];
}

__device__ __forceinline__ void fp8x16_decode(uint4 k, float* o) {
  fp8x4_decode(k.x, o); fp8x4_decode(k.y, o + 4);
  fp8x4_decode(k.z, o + 8); fp8x4_decode(k.w, o + 12);
}

// decode 16 fp8 and dot with 16 v-values held in 4 f32x4 regs
__device__ __forceinline__ float dot16(uint4 k, const f32x4* v4) {
  float o[16];
  fp8x16_decode(k, o);
  float s = 0.f;
#pragma unroll
  for (int q = 0; q < 4; q++)
#pragma unroll
    for (int j = 0; j < 4; j++) s += o[q * 4 + j] * v4[q][j];
  return s;
}

// grid 12288 (zi*4096+row), block 128: row norms + bf16 convert
__global__ __launch_bounds__(128) void prep_kernel(const float* __restrict__ z0, const float* __restrict__ z1,
                                                   const float* __restrict__ z2, short* __restrict__ zb,
                                                   float* __restrict__ sq) {
  int row = blockIdx.x;
  int zi = row >> 12;
  const float* z = (zi == 0) ? z0 : ((zi == 1) ? z1 : z2);
  int r = row & (NN - 1);
  float val = z[r * DD + threadIdx.x];
  zb[row * DD + threadIdx.x] = f32_to_bf16(val);
  float s = wave_reduce_sum(val * val);
  __shared__ float red[2];
  if ((threadIdx.x & 63) == 0) red[threadIdx.x >> 6] = s;
  __syncthreads();
  if (threadIdx.x == 0) sq[row] = red[0] + red[1];
}

// grid dim3(32,32,3), block 256: 128x128 tile via LDS-staged MFMA; K=fp8(exp(-C/reg));
// epilogue also accumulates column sums into t0 (t0 pre-zeroed) => t0 = K^T * ones = t for u0=1
__global__ __launch_bounds__(256) void kbuild_kernel(const short* __restrict__ zb, const float* __restrict__ sq,
                                                     unsigned char* __restrict__ K, float* __restrict__ t0) {
  int p = blockIdx.z;
  int ai = (p == 2) ? 1 : 0;            // pairs (0,1),(0,2),(1,2)
  int bi = (p == 0) ? 1 : 2;
  const short* xg = zb + ai * NN * DD + blockIdx.y * 128 * DD;
  const short* yg = zb + bi * NN * DD + blockIdx.x * 128 * DD;
  const float* sqx = sq + ai * NN + blockIdx.y * 128;
  const float* sqy = sq + bi * NN + blockIdx.x * 128;
  __shared__ short xs[128 * KPAD];
  __shared__ short ys[128 * KPAD];
  __shared__ float colsum[128];
  int tid = threadIdx.x;
  for (int i = tid; i < 2048; i += 256) {  // 128 rows x 16 chunks of 16B, tiles contiguous in global
    int row = i >> 4, seg = i & 15;
    *(uint4*)&xs[row * KPAD + seg * 8] = *(const uint4*)&xg[row * DD + seg * 8];
    *(uint4*)&ys[row * KPAD + seg * 8] = *(const uint4*)&yg[row * DD + seg * 8];
  }
  if (tid < 128) colsum[tid] = 0.f;
  __syncthreads();
  int w = tid >> 6, lane = tid & 63;
  int wr = (w >> 1) * 64, wc = (w & 1) * 64;   // wave quadrant
  int lrow = lane & 15, lk = lane >> 4;
  f32x4 acc[4][4];
#pragma unroll
  for (int i = 0; i < 4; i++)
#pragma unroll
    for (int j = 0; j < 4; j++) acc[i][j] = (f32x4){0.f, 0.f, 0.f, 0.f};
#pragma unroll
  for (int kk = 0; kk < 4; kk++) {
    s16x8 a[4], b[4];
#pragma unroll
    for (int rt = 0; rt < 4; rt++) {
      a[rt] = *(const s16x8*)&xs[(wr + rt * 16 + lrow) * KPAD + kk * 32 + lk * 8];
      b[rt] = *(const s16x8*)&ys[(wc + rt * 16 + lrow) * KPAD + kk * 32 + lk * 8];
    }
#pragma unroll
    for (int rt = 0; rt < 4; rt++)
#pragma unroll
      for (int ct = 0; ct < 4; ct++)
        acc[rt][ct] = __builtin_amdgcn_mfma_f32_16x16x32_bf16(a[rt], b[ct], acc[rt][ct], 0, 0, 0);
  }
  unsigned char* Kp = K + (size_t)p * NN * NN;
#pragma unroll
  for (int ct = 0; ct < 4; ct++) {
    int coll = wc + ct * 16 + lrow;
    int colg = blockIdx.x * 128 + coll;
    float sy = sqy[coll];
    float cs = 0.f;
#pragma unroll
    for (int rt = 0; rt < 4; rt++) {
#pragma unroll
      for (int r = 0; r < 4; r++) {
        int rowl = wr + rt * 16 + lk * 4 + r;
        float Cv = fmaxf(sqx[rowl] + sy - 2.0f * acc[rt][ct][r], 0.0f);
        float kf = __expf(Cv * (-1.0f / REGC));
        cs += kf;
        int pk = __builtin_amdgcn_cvt_pk_fp8_f32(kf, kf, 0, false);
        Kp[(size_t)(blockIdx.y * 128 + rowl) * NN + colg] = (unsigned char)(pk & 0xFF);
      }
    }
    cs += __shfl_xor(cs, 16, 64);
    cs += __shfl_xor(cs, 32, 64);
    if (lk == 0) atomicAdd(&colsum[coll], cs);
  }
  __syncthreads();
  if (tid < 128) atomicAdd(&t0[p * NN + blockIdx.x * 128 + tid], colsum[tid]);
}

// grid 384 (p*128 + rb), block 256, 32 rows/block. One full Sinkhorn iteration:
//   v = nu/(tin+eps) (per-lane regs); u = mu/(Kv+eps); tadd += K^T u (atomics); zero tzero slice
__global__ __launch_bounds__(256) void sink_fused(const unsigned char* __restrict__ K,
                                                  const float* __restrict__ tin, float* __restrict__ tadd,
                                                  float* __restrict__ tzero, float* __restrict__ u) {
  int bid = blockIdx.x;
  int p = bid >> 7;
  int rb = bid & 127;
  int tid = threadIdx.x;
  int w = tid >> 6, lane = tid & 63;
  if (tid < 32) tzero[bid * 32 + tid] = 0.f;   // 384*32 = 12288 = 3*NN
  // phase A: v for this lane's 64 columns (c*1024 + lane*16 + j)
  const float* tp = tin + p * NN;
  f32x4 vr[16];
#pragma unroll
  for (int c = 0; c < 4; c++) {
#pragma unroll
    for (int q = 0; q < 4; q++) {
      f32x4 tv = *(const f32x4*)&tp[c * 1024 + lane * 16 + q * 4];
      f32x4 o;
#pragma unroll
      for (int j = 0; j < 4; j++) o[j] = (1.0f / NN) * __builtin_amdgcn_rcpf(tv[j] + EPSC);
      vr[c * 4 + q] = o;
    }
  }
  __shared__ float ulds[32];
  const unsigned char* Kp = K + (size_t)p * NN * NN;
  int r0 = rb * 32;
  // phase B: wave w handles rows r0 + w*8 .. +7, software-pipelined
  {
    const unsigned char* kr = Kp + (size_t)(r0 + w * 8) * NN + lane * 16;
    uint4 ka0 = *(const uint4*)kr;
    uint4 ka1 = *(const uint4*)(kr + 1024);
    uint4 ka2 = *(const uint4*)(kr + 2048);
    uint4 ka3 = *(const uint4*)(kr + 3072);
#pragma unroll
    for (int rr = 0; rr < 8; rr++) {
      uint4 kb0, kb1, kb2, kb3;
      if (rr < 7) {
        const unsigned char* kn = kr + (size_t)(rr + 1) * NN;
        kb0 = *(const uint4*)kn;
        kb1 = *(const uint4*)(kn + 1024);
        kb2 = *(const uint4*)(kn + 2048);
        kb3 = *(const uint4*)(kn + 3072);
      }
      float acc = dot16(ka0, vr) + dot16(ka1, vr + 4) + dot16(ka2, vr + 8) + dot16(ka3, vr + 12);
      acc = wave_reduce_sum(acc);
      if (lane == 0) {
        float un = (1.0f / NN) / (acc + EPSC);
        ulds[w * 8 + rr] = un;
        u[p * NN + r0 + w * 8 + rr] = un;
      }
      ka0 = kb0; ka1 = kb1; ka2 = kb2; ka3 = kb3;
    }
  }
  __syncthreads();
  // phase C: thread owns cols tid*16..+15, accumulate over the block's 32 rows
  float ca[16];
#pragma unroll
  for (int j = 0; j < 16; j++) ca[j] = 0.f;
  int c0 = tid * 16;
  const unsigned char* kc = Kp + (size_t)r0 * NN + c0;
#pragma unroll 4
  for (int r = 0; r < 32; r++) {
    uint4 k = *(const uint4*)(kc + (size_t)r * NN);
    float ur = ulds[r];
    float kd[16];
    fp8x16_decode(k, kd);
#pragma unroll
    for (int j = 0; j < 16; j++) ca[j] += kd[j] * ur;
  }
  float* td = tadd + p * NN + c0;
#pragma unroll
  for (int j = 0; j < 16; j++) atomicAdd(&td[j], ca[j]);
}

// grid 768 (p*256+rb), block 256, 16 rows/block: loss += u_i K_ij v_j C_ij, C=-reg*ln(K)
__global__ __launch_bounds__(256) void loss_kernel(const unsigned char* __restrict__ K,
                                                   const float* __restrict__ tin, const float* __restrict__ u,
                                                   float* __restrict__ out) {
  int bid = blockIdx.x;
  int p = bid >> 8;
  int rb = bid & 255;
  int tid = threadIdx.x;
  int w = tid >> 6, lane = tid & 63;
  const float* tp = tin + p * NN;
  f32x4 vr[16];
#pragma unroll
  for (int c = 0; c < 4; c++) {
#pragma unroll
    for (int q = 0; q < 4; q++) {
      f32x4 tv = *(const f32x4*)&tp[c * 1024 + lane * 16 + q * 4];
      f32x4 o;
#pragma unroll
      for (int j = 0; j < 4; j++) o[j] = (1.0f / NN) * __builtin_amdgcn_rcpf(tv[j] + EPSC);
      vr[c * 4 + q] = o;
    }
  }
  const unsigned char* Kp = K + (size_t)p * NN * NN;
  const float* up = u + p * NN;
  float lt = 0.f;
#pragma unroll
  for (int rr = 0; rr < 4; rr++) {
    int row = rb * 16 + w * 4 + rr;
    const unsigned char* kr = Kp + (size_t)row * NN + lane * 16;
    float racc = 0.f;
#pragma unroll
    for (int c = 0; c < 4; c++) {
      uint4 k = *(const uint4*)(kr + c * 1024);
      float kd[16];
      fp8x16_decode(k, kd);
#pragma unroll
      for (int q = 0; q < 4; q++)
#pragma unroll
        for (int j = 0; j < 4; j++) {
          float kf = kd[q * 4 + j];
          racc += kf * vr[c * 4 + q][j] * (-REGC * __logf(kf));
        }
    }
    lt += up[row] * racc;
  }
  lt = wave_reduce_sum(lt);
  __shared__ float red[4];
  if (lane == 0) red[w] = lt;
  __syncthreads();
  if (tid == 0) atomicAdd(out, (red[0] + red[1] + red[2] + red[3]) * (1.0f / 3.0f));
}

extern "C" void kernel_launch(void* const* d_in, const int* in_sizes, int n_in,
                              void* d_out, int out_size, void* d_ws, size_t ws_size,
                              hipStream_t stream) {
  const float* z0 = (const float*)d_in[0];
  const float* z1 = (const float*)d_in[1];
  const float* z2 = (const float*)d_in[2];
  float* out = (float*)d_out;
  char* ws = (char*)d_ws;

  const size_t K_BYTES = (size_t)3 * NN * NN;            // 50331648 (fp8)
  unsigned char* K = (unsigned char*)ws;
  short* zb = (short*)(ws + K_BYTES);                    // 3145728 B
  float* sq = (float*)(ws + K_BYTES + 3145728);          // 49152 B
  float* u = (float*)(ws + K_BYTES + 3145728 + 49152);   // 49152 B
  float* tb = (float*)(ws + K_BYTES + 3145728 + 2 * 49152);  // 3 bufs x 3 pairs x 4096 f32

  hipMemsetAsync(d_out, 0, sizeof(float), stream);
  hipMemsetAsync(tb, 0, 3 * 3 * NN * sizeof(float), stream);

  prep_kernel<<<3 * NN, 128, 0, stream>>>(z0, z1, z2, zb, sq);
  kbuild_kernel<<<dim3(32, 32, 3), 256, 0, stream>>>(zb, sq, K, tb /* buf0 = t for u=1 */);

  // 3-buffer rotation: iter i reads buf[i%3], atomically adds into buf[(i+1)%3]
  // (pre-zeroed by iter i-1 or the initial memset), zeroes buf[(i+2)%3]
  for (int i = 0; i < NSINK; i++) {
    float* tin = tb + (size_t)(i % 3) * 3 * NN;
    float* tadd = tb + (size_t)((i + 1) % 3) * 3 * NN;
    float* tzero = tb + (size_t)((i + 2) % 3) * 3 * NN;
    sink_fused<<<384, 256, 0, stream>>>(K, tin, tadd, tzero, u);
  }
  // final v comes from the t-buffer the last iteration READ
  float* tlast = tb + (size_t)((NSINK - 1) % 3) * 3 * NN;
  loss_kernel<<<768, 256, 0, stream>>>(K, tlast, u, out);
}